// Round 1
// baseline (237.800 us; speedup 1.0000x reference)
//
#include <hip/hip_runtime.h>
#include <hip/hip_bf16.h>

#define HH 7
#define NMID 19

__global__ __launch_bounds__(256) void net_mlp_kernel(
    const float* __restrict__ x,
    const float* __restrict__ W1, const float* __restrict__ b1,
    const float* __restrict__ Wm, const float* __restrict__ bm,
    const float* __restrict__ Wo, const float* __restrict__ bo,
    float* __restrict__ out, int B)
{
    int i = blockIdx.x * blockDim.x + threadIdx.x;
    if (i >= B) return;

    const float2 xin = reinterpret_cast<const float2*>(x)[i];

    float h[HH];

    // fc1: Linear(2,7) + ELU
#pragma unroll
    for (int j = 0; j < HH; ++j) {
        float a = fmaf(xin.x, W1[j * 2 + 0], fmaf(xin.y, W1[j * 2 + 1], b1[j]));
        h[j] = (a > 0.0f) ? a : (__expf(a) - 1.0f);
    }

    // fc2..fc20: 19 x Linear(7,7) + ELU, fully unrolled -> uniform weight
    // indices become scalar loads (s_load) feeding v_fmac with SGPR operand.
#pragma unroll
    for (int l = 0; l < NMID; ++l) {
        const float* __restrict__ W = Wm + l * (HH * HH);
        const float* __restrict__ b = bm + l * HH;
        float nh[HH];
#pragma unroll
        for (int j = 0; j < HH; ++j) {
            float a = b[j];
#pragma unroll
            for (int k = 0; k < HH; ++k)
                a = fmaf(h[k], W[j * HH + k], a);
            nh[j] = (a > 0.0f) ? a : (__expf(a) - 1.0f);
        }
#pragma unroll
        for (int j = 0; j < HH; ++j) h[j] = nh[j];
    }

    // fc21: Linear(7,2) + log_softmax over 2 classes
    float l0 = bo[0], l1 = bo[1];
#pragma unroll
    for (int k = 0; k < HH; ++k) {
        l0 = fmaf(h[k], Wo[k], l0);
        l1 = fmaf(h[k], Wo[HH + k], l1);
    }
    float m = fmaxf(l0, l1);
    float z = m + __logf(__expf(l0 - m) + __expf(l1 - m));  // logsumexp, stable

    float2 o;
    o.x = l0 - z;
    o.y = l1 - z;
    reinterpret_cast<float2*>(out)[i] = o;
}

extern "C" void kernel_launch(void* const* d_in, const int* in_sizes, int n_in,
                              void* d_out, int out_size, void* d_ws, size_t ws_size,
                              hipStream_t stream) {
    const float* x  = (const float*)d_in[0];
    const float* W1 = (const float*)d_in[1];
    const float* b1 = (const float*)d_in[2];
    const float* Wm = (const float*)d_in[3];
    const float* bm = (const float*)d_in[4];
    const float* Wo = (const float*)d_in[5];
    const float* bo = (const float*)d_in[6];
    float* out = (float*)d_out;

    const int B = in_sizes[0] / 2;  // x is [B,2]
    const int block = 256;
    const int grid = (B + block - 1) / block;
    net_mlp_kernel<<<grid, block, 0, stream>>>(x, W1, b1, Wm, bm, Wo, bo, out, B);
}